// Round 9
// baseline (146.565 us; speedup 1.0000x reference)
//
#include <hip/hip_runtime.h>
#include <hip/hip_bf16.h>

typedef __attribute__((ext_vector_type(8))) short short8;
typedef __attribute__((ext_vector_type(4))) float f32x4;

#define ALPHA 0.2f
#define NEG_INF -9e15f
#define ROWS 48               // staged h rows per tile
#define OUT 46                // output rows per tile
#define NTILES 1425           // ceil(65536/46)
#define NB 4
#define NN 65536
#define TOT (NTILES * NB)     // 5700
#define GRID 768              // persistent, 3 blocks/CU

typedef __attribute__((address_space(3))) void as3_void;
typedef const __attribute__((address_space(1))) void as1_void;

__device__ __forceinline__ short fb(float x) {
    __hip_bfloat16 b = __float2bfloat16(x);
    return __builtin_bit_cast(short, b);
}
__device__ __forceinline__ float bf2f(unsigned short x) {
    union { unsigned int u; float f; } v; v.u = ((unsigned int)x) << 16;
    return v.f;
}

// prep: W -> bf16 B-fragment table (frag fi = kk*8+q, q = 16-col block) at
// shorts[0..16383]; [Wa1|Wa2|0..] column-fragment table at shorts[16384..].
__global__ __launch_bounds__(256) void prep_w(const float* __restrict__ W,
                                              const float* __restrict__ a,
                                              unsigned short* __restrict__ ws) {
    const int t = threadIdx.x;
    if (blockIdx.x < 8) {
        int qg = blockIdx.x * 256 + t;       // 0..2047
        int lane = qg & 63, fi = qg >> 6;
        int q = fi & 7, kk = fi >> 3;
        int n = q * 16 + (lane & 15);
        int k0 = kk * 32 + ((lane >> 4) & 3) * 8;
        short8 o;
        #pragma unroll
        for (int j = 0; j < 8; ++j) o[j] = fb(W[(k0 + j) * 128 + n]);
        *(short8*)(ws + (size_t)qg * 8) = o;
    } else {
        __shared__ float wa[2][128];
        {
            int k = t >> 1, sel = t & 1;
            const f32x4* wr4 = (const f32x4*)(W + k * 128);
            const f32x4* av4 = (const f32x4*)(a + sel * 128);
            float s = 0.f;
            #pragma unroll
            for (int c4 = 0; c4 < 32; ++c4) {
                f32x4 wv = wr4[c4], av = av4[c4];
                s += wv[0]*av[0] + wv[1]*av[1] + wv[2]*av[2] + wv[3]*av[3];
            }
            wa[sel][k] = s;
        }
        __syncthreads();
        {
            int lane = t & 63, kk = t >> 6;
            int l15 = lane & 15, lg = (lane >> 4) & 3;
            int k0 = kk * 32 + lg * 8;
            short8 o;
            #pragma unroll
            for (int j = 0; j < 8; ++j) o[j] = fb((l15 < 2) ? wa[l15][k0 + j] : 0.f);
            *(short8*)(ws + 16384 + (size_t)t * 8) = o;
        }
    }
}

// Persistent pipelined kernel, 256 threads, 48-row tiles, gload_lds staging,
// 3 blocks/CU. Wave w computes all 48 rows x cols [w*32, w*32+32).
__global__ __launch_bounds__(256, 3)
void gat_fused(const float* __restrict__ h, const int* __restrict__ opm,
               const unsigned short* __restrict__ ws, float* __restrict__ out) {
    __shared__ __align__(16) char Ah[2][24576];  // f32 h tile -> (reused) bf16 Wh
    __shared__ float wh1s[48];
    __shared__ float wh2s[52];                   // row r at 4+r
    __shared__ int maskL[138];

    const int t = threadIdx.x;
    const int lane = t & 63;
    const int w = t >> 6;
    const int l15 = lane & 15;
    const int lg = (lane >> 4) & 3;
    const int C = w << 5;              // col base: 0/32/64/96

    // ---- hoist B fragments (loop-invariant registers, 48 VGPRs) ----
    const short8* wsv  = (const short8*)ws;
    const short8* wsv2 = (const short8*)(ws + 16384);
    short8 bfr[4][2], bfr2[4];
    #pragma unroll
    for (int kk = 0; kk < 4; ++kk) {
        #pragma unroll
        for (int ni = 0; ni < 2; ++ni)
            bfr[kk][ni] = wsv[(size_t)(((kk << 3) + (w << 1) + ni) * 64 + lane)];
        bfr2[kk] = wsv2[(size_t)((kk << 6) + lane)];
    }

    int ti = blockIdx.x;
    int mreg = 0;

    // ---- prologue: stage tile0 h + masks ----
    {
        int b = ti / NTILES;
        int tile = ti - b * NTILES;
        int base = tile * OUT - 1;
        const char* hC = (const char*)(h + (size_t)b * NN * 128);
        #pragma unroll
        for (int i = 0; i < 6; ++i) {
            int p = w * 6 + i;                    // 0..23 chunks (2 rows each)
            int r = (p << 1) + (lane >> 5);
            int g = base + r; if (g < 0) g += NN; else if (g >= NN) g -= NN;
            const char* src = hC + (size_t)g * 512 + ((((lane & 31) << 4)) ^ ((r & 7) << 4));
            __builtin_amdgcn_global_load_lds((as1_void*)src, (as3_void*)&Ah[0][p << 10], 16, 0, 0);
        }
        if (t < 138) {
            int idx = tile * (OUT * 3) + t;
            if (idx > NN * 3 - 1) idx = NN * 3 - 1;
            mreg = opm[(size_t)b * NN * 3 + idx];
        }
    }
    __syncthreads();

    int cur = 0;
    for (; ti < TOT; ti += GRID) {
        const int b = ti / NTILES;
        const int tile = ti - b * NTILES;
        const int row_start = tile * OUT;
        const int base = row_start - 1;
        const int out_rows = min(OUT, NN - row_start);
        float* outB = out + (size_t)b * NN * 128;

        // masks for THIS tile (held in reg since last iter) -> LDS
        if (t < 138) maskL[t] = mreg;

        // ---- issue next tile's prefetch (stays in flight across compute) ----
        const int tn = ti + GRID;
        const bool hn = tn < TOT;
        if (hn) {
            int b2 = tn / NTILES;
            int tile2 = tn - b2 * NTILES;
            int base2 = tile2 * OUT - 1;
            const char* hC2 = (const char*)(h + (size_t)b2 * NN * 128);
            #pragma unroll
            for (int i = 0; i < 6; ++i) {
                int p = w * 6 + i;
                int r = (p << 1) + (lane >> 5);
                int g = base2 + r; if (g < 0) g += NN; else if (g >= NN) g -= NN;
                const char* src = hC2 + (size_t)g * 512 + ((((lane & 31) << 4)) ^ ((r & 7) << 4));
                __builtin_amdgcn_global_load_lds((as1_void*)src, (as3_void*)&Ah[cur ^ 1][p << 10], 16, 0, 0);
            }
            if (t < 138) {
                int idx = tile2 * (OUT * 3) + t;
                if (idx > NN * 3 - 1) idx = NN * 3 - 1;
                mreg = opm[(size_t)b2 * NN * 3 + idx];
            }
        }
        __builtin_amdgcn_sched_barrier(0);

        // ---- GEMM: Wh[48][128] = Ah[cur](f32->bf16) @ W ----
        f32x4 acc[3][2];
        f32x4 acc2[3];
        #pragma unroll
        for (int mi = 0; mi < 3; ++mi) {
            acc2[mi] = (f32x4){0.f, 0.f, 0.f, 0.f};
            #pragma unroll
            for (int ni = 0; ni < 2; ++ni)
                acc[mi][ni] = (f32x4){0.f, 0.f, 0.f, 0.f};
        }
        #pragma unroll
        for (int kk = 0; kk < 4; ++kk) {
            int kb = (kk << 7) + (lg << 5);
            short8 af[3];
            #pragma unroll
            for (int mi = 0; mi < 3; ++mi) {
                int m = (mi << 4) + l15;
                int sw = (m & 7) << 4;
                const char* bp = &Ah[cur][m * 512];
                f32x4 lo = *(const f32x4*)(bp + (kb ^ sw));
                f32x4 hi = *(const f32x4*)(bp + ((kb + 16) ^ sw));
                short8 v;
                v[0] = fb(lo[0]); v[1] = fb(lo[1]); v[2] = fb(lo[2]); v[3] = fb(lo[3]);
                v[4] = fb(hi[0]); v[5] = fb(hi[1]); v[6] = fb(hi[2]); v[7] = fb(hi[3]);
                af[mi] = v;
            }
            #pragma unroll
            for (int mi = 0; mi < 3; ++mi) {
                #pragma unroll
                for (int ni = 0; ni < 2; ++ni)
                    acc[mi][ni] = __builtin_amdgcn_mfma_f32_16x16x32_bf16(
                        af[mi], bfr[kk][ni], acc[mi][ni], 0, 0, 0);
                if (w == 0)
                    acc2[mi] = __builtin_amdgcn_mfma_f32_16x16x32_bf16(
                        af[mi], bfr2[kk], acc2[mi], 0, 0, 0);
            }
        }

        // ---- lgkm-only barrier: all waves done reading Ah[cur]; vm in flight
        __builtin_amdgcn_sched_barrier(0);
        asm volatile("s_waitcnt lgkmcnt(0)" ::: "memory");
        __builtin_amdgcn_s_barrier();
        __builtin_amdgcn_sched_barrier(0);

        // ---- spill Wh (bf16, swizzled) into Ah[cur]; wh1/wh2 from acc2 ----
        {
            char* Bw = &Ah[cur][0];
            #pragma unroll
            for (int mi = 0; mi < 3; ++mi)
                #pragma unroll
                for (int ni = 0; ni < 2; ++ni) {
                    int col = C + (ni << 4) + l15;
                    #pragma unroll
                    for (int j = 0; j < 4; ++j) {
                        int row = (mi << 4) + (lg << 2) + j;
                        *(unsigned short*)(Bw + row * 256 + ((col << 1) ^ ((row & 7) << 4))) =
                            (unsigned short)fb(acc[mi][ni][j]);
                    }
                }
            if (w == 0 && l15 < 2) {
                float* dst = (l15 == 0) ? wh1s : (wh2s + 4);
                #pragma unroll
                for (int mi = 0; mi < 3; ++mi)
                    #pragma unroll
                    for (int j = 0; j < 4; ++j)
                        dst[(mi << 4) + (lg << 2) + j] = acc2[mi][j];
            }
        }
        __builtin_amdgcn_sched_barrier(0);
        asm volatile("s_waitcnt lgkmcnt(0)" ::: "memory");
        __builtin_amdgcn_s_barrier();
        __builtin_amdgcn_sched_barrier(0);

        // ---- combine: inline softmax + coalesced f32x4 stores ----
        const char* Bw = &Ah[cur][0];
        #pragma unroll
        for (int it = 0; it < 6; ++it) {
            int r = 1 + (t >> 5) + (it << 3);
            if (r > out_rows) continue;
            int g = base + r;
            int mk0 = maskL[(r - 1) * 3];
            int mk1 = maskL[(r - 1) * 3 + 1];
            int mk2 = maskL[(r - 1) * 3 + 2];
            float w1 = wh1s[r];
            float e0 = w1 + wh2s[3 + r];
            float e1 = w1 + wh2s[4 + r];
            float e2 = w1 + wh2s[5 + r];
            e0 = e0 > 0.f ? e0 : ALPHA * e0;
            e1 = e1 > 0.f ? e1 : ALPHA * e1;
            e2 = e2 > 0.f ? e2 : ALPHA * e2;
            if (mk0 > 0) e0 = NEG_INF;
            if (mk1 > 0) e1 = NEG_INF;
            if (mk2 > 0) e2 = NEG_INF;
            float m = fmaxf(e0, fmaxf(e1, e2));
            float x0 = __expf(e0 - m), x1 = __expf(e1 - m), x2 = __expf(e2 - m);
            float inv = 1.f / (x0 + x1 + x2);
            float a0 = x0 * inv, a1 = x1 * inv, a2 = x2 * inv;
            int cb = (t & 31) << 3;
            ushort4 wm = *(const ushort4*)(Bw + (r - 1) * 256 + (cb ^ (((r - 1) & 7) << 4)));
            ushort4 w0 = *(const ushort4*)(Bw + r * 256 + (cb ^ ((r & 7) << 4)));
            ushort4 wp = *(const ushort4*)(Bw + (r + 1) * 256 + (cb ^ (((r + 1) & 7) << 4)));
            f32x4 res;
            res[0] = a0 * bf2f(wm.x) + a1 * bf2f(w0.x) + a2 * bf2f(wp.x);
            res[1] = a0 * bf2f(wm.y) + a1 * bf2f(w0.y) + a2 * bf2f(wp.y);
            res[2] = a0 * bf2f(wm.z) + a1 * bf2f(w0.z) + a2 * bf2f(wp.z);
            res[3] = a0 * bf2f(wm.w) + a1 * bf2f(w0.w) + a2 * bf2f(wp.w);
            *(f32x4*)(outB + (size_t)g * 128 + ((t & 31) << 2)) = res;
        }

        // ---- full drain: next tile's h is in LDS after this ----
        __syncthreads();
        cur ^= 1;
    }
}

extern "C" void kernel_launch(void* const* d_in, const int* in_sizes, int n_in,
                              void* d_out, int out_size, void* d_ws, size_t ws_size,
                              hipStream_t stream) {
    const float* h   = (const float*)d_in[0];
    const int*   opm = (const int*)d_in[1];
    const float* W   = (const float*)d_in[2];
    const float* a   = (const float*)d_in[3];
    float* out = (float*)d_out;
    unsigned short* ws = (unsigned short*)d_ws;
    prep_w<<<9, 256, 0, stream>>>(W, a, ws);
    gat_fused<<<GRID, 256, 0, stream>>>(h, opm, ws, out);
}

// Round 10
// 71.286 us; speedup vs baseline: 2.0560x; 2.0560x over previous
//
#include <hip/hip_runtime.h>
#include <hip/hip_bf16.h>

typedef __attribute__((ext_vector_type(8))) short short8;
typedef __attribute__((ext_vector_type(4))) float f32x4;

#define ALPHA 0.2f
#define NEG_INF -9e15f
#define ROWS 48               // staged h rows per tile
#define OUT 46                // output rows per tile
#define NTILES 1425           // ceil(65536/46)
#define NB 4
#define NN 65536
#define TOT (NTILES * NB)     // 5700
#define GRID 768              // persistent, 3 blocks/CU target

typedef __attribute__((address_space(3))) void as3_void;
typedef const __attribute__((address_space(1))) void as1_void;

__device__ __forceinline__ short fb(float x) {
    __hip_bfloat16 b = __float2bfloat16(x);
    return __builtin_bit_cast(short, b);
}

// prep: W -> bf16 B-fragment table (frag fi = kk*8+q, q = 16-col block) at
// shorts[0..16383]; [Wa1|Wa2|0..] column-fragment table at shorts[16384..].
__global__ __launch_bounds__(256) void prep_w(const float* __restrict__ W,
                                              const float* __restrict__ a,
                                              unsigned short* __restrict__ ws) {
    const int t = threadIdx.x;
    if (blockIdx.x < 8) {
        int qg = blockIdx.x * 256 + t;       // 0..2047
        int lane = qg & 63, fi = qg >> 6;
        int q = fi & 7, kk = fi >> 3;
        int n = q * 16 + (lane & 15);
        int k0 = kk * 32 + ((lane >> 4) & 3) * 8;
        short8 o;
        #pragma unroll
        for (int j = 0; j < 8; ++j) o[j] = fb(W[(k0 + j) * 128 + n]);
        *(short8*)(ws + (size_t)qg * 8) = o;
    } else {
        __shared__ float wa[2][128];
        {
            int k = t >> 1, sel = t & 1;
            const f32x4* wr4 = (const f32x4*)(W + k * 128);
            const f32x4* av4 = (const f32x4*)(a + sel * 128);
            float s = 0.f;
            #pragma unroll
            for (int c4 = 0; c4 < 32; ++c4) {
                f32x4 wv = wr4[c4], av = av4[c4];
                s += wv[0]*av[0] + wv[1]*av[1] + wv[2]*av[2] + wv[3]*av[3];
            }
            wa[sel][k] = s;
        }
        __syncthreads();
        {
            int lane = t & 63, kk = t >> 6;
            int l15 = lane & 15, lg = (lane >> 4) & 3;
            int k0 = kk * 32 + lg * 8;
            short8 o;
            #pragma unroll
            for (int j = 0; j < 8; ++j) o[j] = fb((l15 < 2) ? wa[l15][k0 + j] : 0.f);
            *(short8*)(ws + 16384 + (size_t)t * 8) = o;
        }
    }
}

// Persistent pipelined kernel, 256 threads, 48-row tiles, gload_lds staging.
// launch_bounds(256,2): cap 256 so the compiler never spills (it used 128 in
// the working r7 config); occupancy then comes from LDS (50KB -> 3 blocks/CU).
__global__ __launch_bounds__(256, 2)
void gat_fused(const float* __restrict__ h, const int* __restrict__ opm,
               const unsigned short* __restrict__ ws, float* __restrict__ out) {
    __shared__ __align__(16) char Ah[2][24576];  // f32 h tile -> (reused) f32 Wh
    __shared__ float wh1s[48];
    __shared__ float wh2s[52];                   // row r at 4+r
    __shared__ int maskL[138];

    const int t = threadIdx.x;
    const int lane = t & 63;
    const int w = t >> 6;
    const int l15 = lane & 15;
    const int lg = (lane >> 4) & 3;
    const int C = w << 5;              // col base: 0/32/64/96

    // ---- hoist B fragments (loop-invariant registers, 48 VGPRs) ----
    const short8* wsv  = (const short8*)ws;
    const short8* wsv2 = (const short8*)(ws + 16384);
    short8 bfr[4][2], bfr2[4];
    #pragma unroll
    for (int kk = 0; kk < 4; ++kk) {
        #pragma unroll
        for (int ni = 0; ni < 2; ++ni)
            bfr[kk][ni] = wsv[(size_t)(((kk << 3) + (w << 1) + ni) * 64 + lane)];
        bfr2[kk] = wsv2[(size_t)((kk << 6) + lane)];
    }

    int ti = blockIdx.x;
    int mreg = 0;

    // ---- prologue: stage tile0 h + masks ----
    {
        int b = ti / NTILES;
        int tile = ti - b * NTILES;
        int base = tile * OUT - 1;
        const char* hC = (const char*)(h + (size_t)b * NN * 128);
        #pragma unroll
        for (int i = 0; i < 6; ++i) {
            int p = w * 6 + i;                    // 0..23 chunks (2 rows each)
            int r = (p << 1) + (lane >> 5);
            int g = base + r; if (g < 0) g += NN; else if (g >= NN) g -= NN;
            const char* src = hC + (size_t)g * 512 + ((((lane & 31) << 4)) ^ ((r & 7) << 4));
            __builtin_amdgcn_global_load_lds((as1_void*)src, (as3_void*)&Ah[0][p << 10], 16, 0, 0);
        }
        if (t < 138) {
            int idx = tile * (OUT * 3) + t;
            if (idx > NN * 3 - 1) idx = NN * 3 - 1;
            mreg = opm[(size_t)b * NN * 3 + idx];
        }
    }
    __syncthreads();

    int cur = 0;
    for (; ti < TOT; ti += GRID) {
        const int b = ti / NTILES;
        const int tile = ti - b * NTILES;
        const int row_start = tile * OUT;
        const int base = row_start - 1;
        const int out_rows = min(OUT, NN - row_start);
        float* outB = out + (size_t)b * NN * 128;

        // masks for THIS tile (held in reg since last iter) -> LDS
        if (t < 138) maskL[t] = mreg;

        // ---- issue next tile's prefetch (stays in flight across compute) ----
        const int tn = ti + GRID;
        const bool hn = tn < TOT;
        if (hn) {
            int b2 = tn / NTILES;
            int tile2 = tn - b2 * NTILES;
            int base2 = tile2 * OUT - 1;
            const char* hC2 = (const char*)(h + (size_t)b2 * NN * 128);
            #pragma unroll
            for (int i = 0; i < 6; ++i) {
                int p = w * 6 + i;
                int r = (p << 1) + (lane >> 5);
                int g = base2 + r; if (g < 0) g += NN; else if (g >= NN) g -= NN;
                const char* src = hC2 + (size_t)g * 512 + ((((lane & 31) << 4)) ^ ((r & 7) << 4));
                __builtin_amdgcn_global_load_lds((as1_void*)src, (as3_void*)&Ah[cur ^ 1][p << 10], 16, 0, 0);
            }
            if (t < 138) {
                int idx = tile2 * (OUT * 3) + t;
                if (idx > NN * 3 - 1) idx = NN * 3 - 1;
                mreg = opm[(size_t)b2 * NN * 3 + idx];
            }
        }
        __builtin_amdgcn_sched_barrier(0);

        // ---- GEMM: Wh[48][128] = Ah[cur](f32->bf16) @ W ----
        f32x4 acc[3][2];
        f32x4 acc2[3];
        #pragma unroll
        for (int mi = 0; mi < 3; ++mi) {
            acc2[mi] = (f32x4){0.f, 0.f, 0.f, 0.f};
            #pragma unroll
            for (int ni = 0; ni < 2; ++ni)
                acc[mi][ni] = (f32x4){0.f, 0.f, 0.f, 0.f};
        }
        #pragma unroll
        for (int kk = 0; kk < 4; ++kk) {
            int kb = (kk << 7) + (lg << 5);
            short8 af[3];
            #pragma unroll
            for (int mi = 0; mi < 3; ++mi) {
                int m = (mi << 4) + l15;
                int sw = (m & 7) << 4;
                const char* bp = &Ah[cur][m * 512];
                f32x4 lo = *(const f32x4*)(bp + (kb ^ sw));
                f32x4 hi = *(const f32x4*)(bp + ((kb + 16) ^ sw));
                short8 v;
                v[0] = fb(lo[0]); v[1] = fb(lo[1]); v[2] = fb(lo[2]); v[3] = fb(lo[3]);
                v[4] = fb(hi[0]); v[5] = fb(hi[1]); v[6] = fb(hi[2]); v[7] = fb(hi[3]);
                af[mi] = v;
            }
            #pragma unroll
            for (int mi = 0; mi < 3; ++mi) {
                #pragma unroll
                for (int ni = 0; ni < 2; ++ni)
                    acc[mi][ni] = __builtin_amdgcn_mfma_f32_16x16x32_bf16(
                        af[mi], bfr[kk][ni], acc[mi][ni], 0, 0, 0);
                if (w == 0)
                    acc2[mi] = __builtin_amdgcn_mfma_f32_16x16x32_bf16(
                        af[mi], bfr2[kk], acc2[mi], 0, 0, 0);
            }
        }

        // ---- lgkm-only barrier: all waves done reading Ah[cur]; vm in flight
        __builtin_amdgcn_sched_barrier(0);
        asm volatile("s_waitcnt lgkmcnt(0)" ::: "memory");
        __builtin_amdgcn_s_barrier();
        __builtin_amdgcn_sched_barrier(0);

        // ---- spill Wh (f32, swizzled) into Ah[cur]; wh1/wh2 from acc2 ----
        {
            char* Bw = &Ah[cur][0];
            #pragma unroll
            for (int mi = 0; mi < 3; ++mi)
                #pragma unroll
                for (int ni = 0; ni < 2; ++ni) {
                    int col = C + (ni << 4) + l15;
                    #pragma unroll
                    for (int j = 0; j < 4; ++j) {
                        int row = (mi << 4) + (lg << 2) + j;
                        *(float*)(Bw + row * 512 + ((col << 2) ^ ((row & 7) << 4))) =
                            acc[mi][ni][j];
                    }
                }
            if (w == 0 && l15 < 2) {
                float* dst = (l15 == 0) ? wh1s : (wh2s + 4);
                #pragma unroll
                for (int mi = 0; mi < 3; ++mi)
                    #pragma unroll
                    for (int j = 0; j < 4; ++j)
                        dst[(mi << 4) + (lg << 2) + j] = acc2[mi][j];
            }
        }
        __builtin_amdgcn_sched_barrier(0);
        asm volatile("s_waitcnt lgkmcnt(0)" ::: "memory");
        __builtin_amdgcn_s_barrier();
        __builtin_amdgcn_sched_barrier(0);

        // ---- combine: inline softmax + coalesced f32x4 stores ----
        const char* Bw = &Ah[cur][0];
        #pragma unroll
        for (int it = 0; it < 6; ++it) {
            int r = 1 + (t >> 5) + (it << 3);
            if (r > out_rows) continue;
            int g = base + r;
            int mk0 = maskL[(r - 1) * 3];
            int mk1 = maskL[(r - 1) * 3 + 1];
            int mk2 = maskL[(r - 1) * 3 + 2];
            float w1 = wh1s[r];
            float e0 = w1 + wh2s[3 + r];
            float e1 = w1 + wh2s[4 + r];
            float e2 = w1 + wh2s[5 + r];
            e0 = e0 > 0.f ? e0 : ALPHA * e0;
            e1 = e1 > 0.f ? e1 : ALPHA * e1;
            e2 = e2 > 0.f ? e2 : ALPHA * e2;
            if (mk0 > 0) e0 = NEG_INF;
            if (mk1 > 0) e1 = NEG_INF;
            if (mk2 > 0) e2 = NEG_INF;
            float m = fmaxf(e0, fmaxf(e1, e2));
            float x0 = __expf(e0 - m), x1 = __expf(e1 - m), x2 = __expf(e2 - m);
            float inv = 1.f / (x0 + x1 + x2);
            float a0 = x0 * inv, a1 = x1 * inv, a2 = x2 * inv;
            int cb = (t & 31) << 4;
            f32x4 wm = *(const f32x4*)(Bw + (r - 1) * 512 + (cb ^ (((r - 1) & 7) << 4)));
            f32x4 w0 = *(const f32x4*)(Bw + r * 512 + (cb ^ ((r & 7) << 4)));
            f32x4 wp = *(const f32x4*)(Bw + (r + 1) * 512 + (cb ^ (((r + 1) & 7) << 4)));
            f32x4 res;
            #pragma unroll
            for (int j = 0; j < 4; ++j)
                res[j] = a0 * wm[j] + a1 * w0[j] + a2 * wp[j];
            *(f32x4*)(outB + (size_t)g * 128 + ((t & 31) << 2)) = res;
        }

        // ---- full drain: next tile's h is in LDS after this ----
        __syncthreads();
        cur ^= 1;
    }
}

extern "C" void kernel_launch(void* const* d_in, const int* in_sizes, int n_in,
                              void* d_out, int out_size, void* d_ws, size_t ws_size,
                              hipStream_t stream) {
    const float* h   = (const float*)d_in[0];
    const int*   opm = (const int*)d_in[1];
    const float* W   = (const float*)d_in[2];
    const float* a   = (const float*)d_in[3];
    float* out = (float*)d_out;
    unsigned short* ws = (unsigned short*)d_ws;
    prep_w<<<9, 256, 0, stream>>>(W, a, ws);
    gat_fused<<<GRID, 256, 0, stream>>>(h, opm, ws, out);
}